// Round 3
// baseline (177.330 us; speedup 1.0000x reference)
//
#include <hip/hip_runtime.h>
#include <stdint.h>

#define GRAPHS 256
#define NPG    512
#define EPG    8192

typedef __attribute__((ext_vector_type(8))) short s16x8;
typedef __attribute__((ext_vector_type(4))) float f32x4;

__device__ __forceinline__ float bf2f(unsigned short u){
  union { unsigned int i; float f; } c; c.i = ((unsigned int)u)<<16; return c.f;
}
__device__ __forceinline__ unsigned short f2bf(float f){
  union { float f; unsigned int i; } c; c.f = f;
  unsigned int r = c.i + 0x7fffu + ((c.i>>16)&1u);   // RNE (software; do NOT
  return (unsigned short)(r>>16);                    // use v_cvt_pk_bf16_f32)
}

// ---------------- tiny prep: EW1T + W2F (bit-identical to passing R2) ------
__global__ __launch_bounds__(128) void k_prep(const float* __restrict__ emb,
      const float* __restrict__ W1, const float* __restrict__ W2,
      unsigned short* __restrict__ EW1T, unsigned short* __restrict__ W2F){
  const int b = blockIdx.x, tid = threadIdx.x;
  if (tid < 32){                                 // EW1T: serial f32 dot (exact
    const int gid = b*32 + tid;                  //   same order as before)
    const int t = gid>>7, c = gid&127;
    float acc=0.f;
    #pragma unroll 4
    for (int k=0;k<128;k++) acc += emb[t*128+k]*W1[k*128+c];
    EW1T[c*64+t]=f2bf(acc);
  } else if (tid >= 64){                         // W2F fragment order
    const int i = b*64 + (tid-64);
    const int ks = i>>12, nt=(i>>9)&7, ln=(i>>3)&63, j=i&7;
    const int k = ks*32 + (ln>>4)*8 + j;
    const int n = nt*16 + (ln&15);
    W2F[i] = f2bf(W2[k*128+n]);
  }
}

// ---------------- mega kernel: 1 block = 1 graph, everything in LDS --------
// LDS layout (dynamic):
//   sorted16 u16[8192]  (t<<9|src, sorted by dst; dst implied by cs segments)
//   cs i32[513] | wsc f32[512] | wint i32[512] | b1sh/b2sh f32[128]
//   S1 scratch 69632: CSR aux -> Sint[256][68] -> h1sh[256][136] -> A u8[128][264] -> red
//   h2l bf16 65536: H2 of current src-half in agg2-B-fragment layout
#define OFF_SORT 0
#define OFF_CS   16384
#define OFF_WSC  18440
#define OFF_WINT 20488
#define OFF_B1   22536
#define OFF_B2   23048
#define OFF_S1   23568
#define OFF_H2L  93200
#define MEGA_LDS 158736

__global__ __launch_bounds__(512,2) void k_mega(
      const int* __restrict__ src, const int* __restrict__ dst,
      const int* __restrict__ ntype, const float* __restrict__ b1,
      const float* __restrict__ b2, const unsigned short* __restrict__ EW1T,
      const unsigned short* __restrict__ W2F, float* __restrict__ out){
  extern __shared__ char smem[];
  unsigned short* sorted16 = (unsigned short*)(smem + OFF_SORT);
  int*   cs   = (int*)(smem + OFF_CS);
  float* wsc  = (float*)(smem + OFF_WSC);
  int*   wint = (int*)(smem + OFF_WINT);
  float* b1sh = (float*)(smem + OFF_B1);
  float* b2sh = (float*)(smem + OFF_B2);
  char*  S1   = smem + OFF_S1;
  unsigned short* h2l = (unsigned short*)(smem + OFF_H2L);
  // phase-1 aliases (CSR aux)
  int* hist   = (int*)S1;                       // [512]
  int* cursor = hist + 512;                     // [512]
  int* co     = cursor + 512;                   // [512]
  unsigned short* ntype_sh = (unsigned short*)(co + 512); // [512]
  // later aliases
  int* Sint = (int*)S1;                         // [256][68]
  unsigned short* h1sh = (unsigned short*)S1;   // [256][136]
  unsigned char* A = (unsigned char*)S1;        // [128][264]
  unsigned int* A32 = (unsigned int*)S1;
  float* red = (float*)S1;                      // [8][64]

  const int b = blockIdx.x, tid = threadIdx.x;
  const int eb = b*EPG, nb = b*NPG;

  // ================= phase 1: CSR (all in LDS, no global writes) ===========
  hist[tid]=0; co[tid]=0; ntype_sh[tid]=(unsigned short)ntype[nb+tid];
  if (tid<128){ b1sh[tid]=b1[tid]; b2sh[tid]=b2[tid]; }
  __syncthreads();
  int4 d4[4], s4[4];
  {
    const int4* dv = (const int4*)(dst+eb);
    const int4* sv = (const int4*)(src+eb);
    #pragma unroll
    for (int j=0;j<4;j++){
      d4[j]=dv[tid + j*512];
      s4[j]=sv[tid + j*512];
      atomicAdd(&hist[d4[j].x&(NPG-1)],1); atomicAdd(&hist[d4[j].y&(NPG-1)],1);
      atomicAdd(&hist[d4[j].z&(NPG-1)],1); atomicAdd(&hist[d4[j].w&(NPG-1)],1);
      atomicAdd(&co[s4[j].x&(NPG-1)],1);   atomicAdd(&co[s4[j].y&(NPG-1)],1);
      atomicAdd(&co[s4[j].z&(NPG-1)],1);   atomicAdd(&co[s4[j].w&(NPG-1)],1);
    }
  }
  __syncthreads();
  if (tid<64){
    int carry=0;
    #pragma unroll
    for (int c=0;c<8;c++){
      int sc=hist[64*c+tid];
      #pragma unroll
      for (int off=1;off<64;off<<=1){ int y=__shfl_up(sc,off); if (tid>=off) sc+=y; }
      cs[64*c+tid+1]=carry+sc;
      carry+=__shfl(sc,63);
    }
    if (tid==0) cs[0]=0;
  }
  __syncthreads();
  cursor[tid]=cs[tid];
  __syncthreads();
  #pragma unroll
  for (int j=0;j<4;j++){
    int dl, s, pos;
    dl=d4[j].x&(NPG-1); s=s4[j].x&(NPG-1);
    pos=atomicAdd(&cursor[dl],1);
    sorted16[pos]=(unsigned short)(((unsigned int)ntype_sh[s]<<9)|(unsigned int)s);
    dl=d4[j].y&(NPG-1); s=s4[j].y&(NPG-1);
    pos=atomicAdd(&cursor[dl],1);
    sorted16[pos]=(unsigned short)(((unsigned int)ntype_sh[s]<<9)|(unsigned int)s);
    dl=d4[j].z&(NPG-1); s=s4[j].z&(NPG-1);
    pos=atomicAdd(&cursor[dl],1);
    sorted16[pos]=(unsigned short)(((unsigned int)ntype_sh[s]<<9)|(unsigned int)s);
    dl=d4[j].w&(NPG-1); s=s4[j].w&(NPG-1);
    pos=atomicAdd(&cursor[dl],1);
    sorted16[pos]=(unsigned short)(((unsigned int)ntype_sh[s]<<9)|(unsigned int)s);
  }
  {                                             // out-degree isqrt (co valid)
    int a=co[tid]; if(a<1)a=1;
    const float w = rsqrtf((float)a);
    wsc[tid]=w; wint[tid]=(int)(w*1048576.f);   // 2^20 fixed point
  }
  __syncthreads();                              // CSR done; S1 free

  const int wave=tid>>6, lane=tid&63, l16=lane&15, quad=lane>>4;
  const int mg2=wave>>1, ng2=wave&1;            // agg2 map: A-unpack 2x only
  f32x4 acc[4][2][4];                           // [dt][rt][ct], K-persistent
  #pragma unroll
  for (int dt2=0;dt2<4;dt2++)
    #pragma unroll
    for (int rt=0;rt<2;rt++)
      #pragma unroll
      for (int ct=0;ct<4;ct++) acc[dt2][rt][ct]=(f32x4){0.f,0.f,0.f,0.f};

  #pragma unroll 1
  for (int h=0; h<2; ++h){                      // src-half / h1-row-half
    const int v0 = h*256;
    // ---- agg1 scatter: Sint[r][t] += wint[src] ----
    for (int i=tid; i<(256*68)/4; i+=512) ((f32x4*)Sint)[i]=(f32x4){0.f,0.f,0.f,0.f};
    __syncthreads();
    {
      const int r = tid>>1, p = tid&1;          // 2 threads per dst row
      const int e1 = cs[v0+r+1];
      for (int i=cs[v0+r]+p; i<e1; i+=2){
        const unsigned int e = sorted16[i];
        atomicAdd(&Sint[r*68 + (int)(e>>9)], wint[e&511]);
      }
    }
    __syncthreads();
    // ---- pass 1: MFMA(S_hi/lo @ EW1T) ----
    f32x4 acc1[2][8];
    #pragma unroll
    for (int rt=0;rt<2;rt++)
      #pragma unroll
      for (int nt=0;nt<8;nt++) acc1[rt][nt]=(f32x4){0.f,0.f,0.f,0.f};
    #pragma unroll
    for (int kh=0; kh<2; ++kh){
      s16x8 fh[2], fl[2];
      #pragma unroll
      for (int rt=0;rt<2;rt++){
        const int m = (wave*2+rt)*16 + l16;
        const int* sp = &Sint[m*68 + kh*32 + quad*8];
        union { s16x8 v; unsigned short u[8]; } hv, lv;
        #pragma unroll
        for (int j=0;j<8;j++){
          const float f = (float)sp[j] * (1.f/1048576.f);   // exact exp shift
          const unsigned short hi = f2bf(f);
          hv.u[j]=hi; lv.u[j]=f2bf(f - bf2f(hi));
        }
        fh[rt]=hv.v; fl[rt]=lv.v;
      }
      const int kc = kh*32 + quad*8;
      #pragma unroll
      for (int nt=0;nt<8;nt++){                 // one B-frag feeds hi AND lo
        s16x8 bfr=__builtin_bit_cast(s16x8,
            *(const uint4*)(EW1T + (size_t)(nt*16+l16)*64 + kc));
        acc1[0][nt]=__builtin_amdgcn_mfma_f32_16x16x32_bf16(fh[0],bfr,acc1[0][nt],0,0,0);
        acc1[1][nt]=__builtin_amdgcn_mfma_f32_16x16x32_bf16(fh[1],bfr,acc1[1][nt],0,0,0);
        acc1[0][nt]=__builtin_amdgcn_mfma_f32_16x16x32_bf16(fl[0],bfr,acc1[0][nt],0,0,0);
        acc1[1][nt]=__builtin_amdgcn_mfma_f32_16x16x32_bf16(fl[1],bfr,acc1[1][nt],0,0,0);
      }
    }
    // ---- epilogue 1: h1 = relu(agg*isq+b1)*osc -> h1sh ----
    float isq[2][4], os[2][4];
    #pragma unroll
    for (int rt=0;rt<2;rt++){
      const int mloc = (wave*2+rt)*16 + quad*4;
      #pragma unroll
      for (int r=0;r<4;r++){
        int d = cs[v0+mloc+r+1]-cs[v0+mloc+r]; if (d<1) d=1;
        isq[rt][r]=rsqrtf((float)d);
        os[rt][r]=wsc[v0+mloc+r];
      }
    }
    __syncthreads();                            // all Sint reads done
    #pragma unroll
    for (int rt=0;rt<2;rt++){
      const int mloc = (wave*2+rt)*16 + quad*4;
      #pragma unroll
      for (int nt=0;nt<8;nt++){
        const int col = nt*16+l16;
        const float bb = b1sh[col];
        #pragma unroll
        for (int r=0;r<4;r++){
          const float v = fmaxf(acc1[rt][nt][r]*isq[rt][r]+bb,0.f)*os[rt][r];
          h1sh[(mloc+r)*136 + col] = f2bf(v);
        }
      }
    }
    __syncthreads();
    // ---- pass 2: H2 = h1 @ W2 -> h2l (LDS, B-fragment layout) ----
    f32x4 acc2[2][8];
    #pragma unroll
    for (int rt=0;rt<2;rt++)
      #pragma unroll
      for (int nt=0;nt<8;nt++) acc2[rt][nt]=(f32x4){0.f,0.f,0.f,0.f};
    #pragma unroll
    for (int ks=0; ks<4; ++ks){
      s16x8 a2[2];
      #pragma unroll
      for (int rt=0;rt<2;rt++){
        const int m = (wave*2+rt)*16 + l16;
        a2[rt]=__builtin_bit_cast(s16x8,
            *(const uint4*)(h1sh + m*136 + ks*32 + quad*8));
      }
      #pragma unroll
      for (int nt=0;nt<8;nt++){
        s16x8 bfr=__builtin_bit_cast(s16x8,
            *(const uint4*)(W2F + (size_t)(((ks*8+nt)*64)+lane)*8));
        #pragma unroll
        for (int rt=0;rt<2;rt++)
          acc2[rt][nt]=__builtin_amdgcn_mfma_f32_16x16x32_bf16(a2[rt],bfr,acc2[rt][nt],0,0,0);
      }
    }
    // epilogue 2: write h2l in B-frag order (local ks2 = W>>1, K=256)
    #pragma unroll
    for (int rt=0;rt<2;rt++){
      const int W = wave*2+rt;
      const int ks2 = W>>1;
      const int q2  = ((W&1)<<1) | (quad>>1);
      const int j0  = (quad&1)*4;
      #pragma unroll
      for (int nt=0;nt<8;nt++){
        ushort4 st;
        st.x=f2bf(acc2[rt][nt][0]); st.y=f2bf(acc2[rt][nt][1]);
        st.z=f2bf(acc2[rt][nt][2]); st.w=f2bf(acc2[rt][nt][3]);
        *(ushort4*)(h2l + (size_t)(((ks2*8+nt)*64 + q2*16 + l16)*8 + j0)) = st;
      }
    }
    __syncthreads();                            // h1sh reads + h2l writes done
    // ---- agg2: counts(dst-tile, src-half) @ h2l, accumulate into acc ----
    #pragma unroll
    for (int dt=0; dt<4; ++dt){
      for (int i=tid; i<(128*264)/16; i+=512) ((uint4*)A)[i]=(uint4){0u,0u,0u,0u};
      __syncthreads();
      {
        const int r = tid>>2, p = tid&3;        // 4 threads per dst row
        const int e1 = cs[dt*128+r+1];
        for (int i=cs[dt*128+r]+p; i<e1; i+=4){
          const int s = (int)(sorted16[i] & 511u);
          if ((s>>8)==h)
            atomicAdd(&A32[r*66 + ((s&255)>>2)], 1u<<((s&3)*8));
        }
      }
      __syncthreads();
      const unsigned char* Ab0 = A + ((mg2*2+0)*16 + l16)*264 + quad*8;
      const unsigned char* Ab1 = A + ((mg2*2+1)*16 + l16)*264 + quad*8;
      #pragma unroll
      for (int ks=0; ks<8; ++ks){
        uint4 bq[4];
        #pragma unroll
        for (int ct=0;ct<4;ct++)
          bq[ct] = *(const uint4*)(h2l + (size_t)(((ks*8 + ng2*4+ct)*64 + lane)*8));
        #pragma unroll
        for (int rt=0;rt<2;rt++){
          const uint2 aw = *(const uint2*)((rt ? Ab1 : Ab0) + ks*32);
          union { s16x8 v; unsigned int u[4]; } pk;
          {
            const float g0=(float)( aw.x       &0xffu);
            const float g1=(float)((aw.x>> 8u) &0xffu);
            const float g2=(float)((aw.x>>16u) &0xffu);
            const float g3=(float)( aw.x>>24u        );
            pk.u[0]=__builtin_amdgcn_perm(__builtin_bit_cast(unsigned int,g1),
                                          __builtin_bit_cast(unsigned int,g0),0x07060302u);
            pk.u[1]=__builtin_amdgcn_perm(__builtin_bit_cast(unsigned int,g3),
                                          __builtin_bit_cast(unsigned int,g2),0x07060302u);
          }
          {
            const float g0=(float)( aw.y       &0xffu);
            const float g1=(float)((aw.y>> 8u) &0xffu);
            const float g2=(float)((aw.y>>16u) &0xffu);
            const float g3=(float)( aw.y>>24u        );
            pk.u[2]=__builtin_amdgcn_perm(__builtin_bit_cast(unsigned int,g1),
                                          __builtin_bit_cast(unsigned int,g0),0x07060302u);
            pk.u[3]=__builtin_amdgcn_perm(__builtin_bit_cast(unsigned int,g3),
                                          __builtin_bit_cast(unsigned int,g2),0x07060302u);
          }
          #pragma unroll
          for (int ct=0;ct<4;ct++)
            acc[dt][rt][ct]=__builtin_amdgcn_mfma_f32_16x16x32_bf16(pk.v,
                __builtin_bit_cast(s16x8, bq[ct]), acc[dt][rt][ct],0,0,0);
        }
      }
      __syncthreads();                          // A reads done before next zero
    }
  } // h

  // ================= final epilogue: relu + column mean -> out =============
  float p[4]; p[0]=0.f; p[1]=0.f; p[2]=0.f; p[3]=0.f;
  #pragma unroll
  for (int dt=0; dt<4; ++dt){
    #pragma unroll
    for (int rt=0;rt<2;rt++){
      const int mrow = dt*128 + (mg2*2+rt)*16 + quad*4;
      float isq2[4];
      #pragma unroll
      for (int r=0;r<4;r++){
        int d=cs[mrow+r+1]-cs[mrow+r]; if (d<1) d=1;
        isq2[r]=rsqrtf((float)d);
      }
      #pragma unroll
      for (int ct=0;ct<4;ct++){
        const int col=(ng2*4+ct)*16 + l16;
        const float bb = b2sh[col];
        #pragma unroll
        for (int r=0;r<4;r++)
          p[ct] += fmaxf(acc[dt][rt][ct][r]*isq2[r]+bb,0.f);
      }
    }
  }
  #pragma unroll
  for (int ct=0;ct<4;ct++){
    p[ct] += __shfl_xor(p[ct],16);              // reduce rows across quads
    p[ct] += __shfl_xor(p[ct],32);
  }
  __syncthreads();                              // all A reads done; red aliases
  if (quad==0){
    #pragma unroll
    for (int ct=0;ct<4;ct++) red[wave*64 + ct*16 + l16] = p[ct];
  }
  __syncthreads();
  if (tid<128){
    const int col=tid, ngc=col>>6, c6=col&63;
    float s=0.f;
    #pragma unroll
    for (int k=0;k<4;k++) s += red[(2*k+ngc)*64 + c6];
    out[(size_t)b*128 + col] = s*(1.f/512.f);
  }
}

extern "C" void kernel_launch(void* const* d_in, const int* in_sizes, int n_in,
                              void* d_out, int out_size, void* d_ws, size_t ws_size,
                              hipStream_t stream){
  const int* node_feat = (const int*)d_in[0];
  const int* src = (const int*)d_in[1];
  const int* dst = (const int*)d_in[2];
  const float* emb = (const float*)d_in[3];
  const float* W1  = (const float*)d_in[4];
  const float* b1  = (const float*)d_in[5];
  const float* W2  = (const float*)d_in[6];
  const float* b2  = (const float*)d_in[7];

  char* ws = (char*)d_ws;
  unsigned short* EW1T = (unsigned short*)(ws);            // 16384 B
  unsigned short* W2F  = (unsigned short*)(ws + 16384);    // 32768 B

  (void)hipFuncSetAttribute(reinterpret_cast<const void*>(&k_mega),
        hipFuncAttributeMaxDynamicSharedMemorySize, MEGA_LDS);

  k_prep<<<GRAPHS,128,0,stream>>>(emb,W1,W2,EW1T,W2F);
  k_mega<<<GRAPHS,512,MEGA_LDS,stream>>>(src,dst,node_feat,b1,b2,EW1T,W2F,
        (float*)d_out);
}